// Round 7
// baseline (220.884 us; speedup 1.0000x reference)
//
#include <hip/hip_runtime.h>
#include <stdint.h>

#define B_ 256
#define H_ 600
#define W_ 19
#define C1_ 40
#define C2_ 40
#define KH_ 29
#define PAD_ 14
#define NW_ 760       // C1_*W_
#define NWORDS_ 12    // ceil(760/64)
#define NJ_ 39
#define FIN_ 1560     // C2_*NJ_
#define FOUT_ 80
#define FCW_ 25       // ceil(1560/64)
#define HS1 150       // h rows per k1 block
#define XSTL 179      // LDS column stride (odd => bank spread)

__device__ __forceinline__ float fsgn(float x){ return (x > 0.f) ? 1.f : ((x < 0.f) ? -1.f : 0.f); }
__device__ __forceinline__ int8_t isgn(float x){ return (int8_t)((x > 0.f) - (x < 0.f)); }

// bnp layout: [0:40) s1, [40:80) t1, [80:120) s2, [120:160) t2, [160:240) s3, [240:320) t3
// s1bits layout: [b][wd][h] ulonglong2 {P, M}; bit idx within plane = w*40 + c1
__global__ void k0_setup(const float* __restrict__ w1, const float* __restrict__ w2,
                         const float* __restrict__ fc1w, const float* __restrict__ fc2w,
                         const float* __restrict__ g1, const float* __restrict__ b1,
                         const float* __restrict__ m1, const float* __restrict__ v1,
                         const float* __restrict__ g2, const float* __restrict__ b2,
                         const float* __restrict__ m2, const float* __restrict__ v2,
                         const float* __restrict__ g3, const float* __restrict__ b3,
                         const float* __restrict__ m3, const float* __restrict__ v3,
                         float* __restrict__ w1s, uint64_t* __restrict__ w2m,
                         uint64_t* __restrict__ fc1p, int8_t* __restrict__ fc2s,
                         float* __restrict__ bnp)
{
  int tid = blockIdx.x * blockDim.x + threadIdx.x;
  int np  = gridDim.x * blockDim.x;
  int lane = threadIdx.x & 63;
  int gw   = tid >> 6;
  int nw   = np >> 6;

  for (int i = tid; i < C1_*KH_; i += np) w1s[i] = fsgn(w1[i]);

  // w2 pos plane only (weights never 0 => neg = ~pos within M); bit idx = w*40+c1
  for (int v = gw; v < C2_*NWORDS_; v += nw){
    int c2 = v / NWORDS_, wd = v % NWORDS_;
    int idx = wd*64 + lane;
    float val = 0.f;
    if (idx < NW_){
      int c1 = idx % 40, w = idx / 40;
      val = w2[c2*NW_ + c1*W_ + w];
    }
    unsigned long long m = __ballot(val > 0.f);
    if (lane == 0) w2m[c2*NWORDS_ + wd] = m;
  }
  // fc1 bit planes: fc1p[o*50 + wd]=pos, [o*50+25+wd]=neg
  for (int v = gw; v < FOUT_*2*FCW_; v += nw){
    int o = v / (2*FCW_), r = v % (2*FCW_);
    int neg = r / FCW_, wd = r % FCW_;
    int e = wd*64 + lane;
    float val = (e < FIN_) ? fc1w[o*FIN_ + e] : 0.f;
    unsigned long long m = __ballot(neg ? (val < 0.f) : (val > 0.f));
    if (lane == 0) fc1p[o*(2*FCW_) + r] = m;
  }
  for (int i = tid; i < 2*FOUT_; i += np) fc2s[i] = isgn(fc2w[i]);
  for (int i = tid; i < C1_; i += np){
    float s = __fdiv_rn(g1[i], __fsqrt_rn(__fadd_rn(v1[i], 1e-5f)));
    bnp[i] = s; bnp[40+i] = __fsub_rn(b1[i], __fmul_rn(m1[i], s));
  }
  for (int i = tid; i < C2_; i += np){
    float s = __fdiv_rn(g2[i], __fsqrt_rn(__fadd_rn(v2[i], 1e-5f)));
    bnp[80+i] = s; bnp[120+i] = __fsub_rn(b2[i], __fmul_rn(m2[i], s));
  }
  for (int i = tid; i < FOUT_; i += np){
    float s = __fdiv_rn(g3[i], __fsqrt_rn(__fadd_rn(v3[i], 1e-5f)));
    bnp[160+i] = s; bnp[240+i] = __fsub_rn(b3[i], __fmul_rn(m3[i], s));
  }
}

// ---- k1: conv1 via register-rotation sliding window ----
// asm keep-alive makes each loaded value opaque => compiler can't rematerialize
// the LDS read, forcing a true register-resident window (the r6 failure mode).
__device__ __forceinline__ float opaque(float v){ asm volatile("" : "+v"(v)); return v; }

template<int T>
__device__ __forceinline__ float acc29(float (&xw)[29], float (&wt)[29]){
  float a = 0.f;
  #pragma unroll
  for (int k = 0; k < 29; ++k)
    a = __builtin_fmaf(wt[k], xw[(T + k) % 29], a);   // ascending k: bit-exact chain
  return a;
}

template<int T>
__device__ __forceinline__ void step1(float (&xw)[29], float (&wt)[29],
                                      const float* xck, ulonglong2* ob,
                                      float scale, float bias, int lane){
  xw[(T + 28) % 29] = opaque(xck[T + 28]);            // 1 ds_read_b32, pinned in a reg
  float acc = acc29<T>(xw, wt);
  float z = __fadd_rn(__fmul_rn(acc, scale), bias);   // sign(prelu(z)) == sign(z)
  unsigned long long pp = __ballot(z > 0.f);          // NaN (invalid lanes) -> false
  unsigned long long nn = __ballot(z < 0.f);
  if (lane == 0){ ulonglong2 v; v.x = pp; v.y = pp | nn; ob[T] = v; }
}

#define S1(t) step1<t>(xw, wt, xck, ob, scale, bias, lane);

__global__ __launch_bounds__(256, 6) void k1_conv1(const float* __restrict__ x,
                                                   const float* __restrict__ w1s,
                                                   const float* __restrict__ bnp,
                                                   uint64_t* __restrict__ s1bits)
{
  __shared__ float xs[W_ * XSTL];      // transposed: xs[w*XSTL + r], r = gh - h0 + 14
  int b = blockIdx.x, ht = blockIdx.y, g = blockIdx.z;
  int h0 = HS1 * ht;
  const float* xb = x + (size_t)b * H_ * W_;
  for (int i = threadIdx.x; i < (HS1 + 28) * W_; i += 256){
    int r = i / W_, w = i % W_;
    int gh = h0 - PAD_ + r;
    xs[w*XSTL + r] = (gh >= 0 && gh < H_) ? xb[gh*W_ + w] : 0.f;
  }
  __syncthreads();

  int lane = threadIdx.x & 63, wave = threadIdx.x >> 6;  // 4 waves/block
  int wd   = g*4 + wave;                                 // this wave's bit-word (0..11)
  int idx  = wd*64 + lane;
  bool valid = (idx < NW_);
  int c1 = idx % 40;
  int w  = valid ? (idx / 40) : 18;

  float wt[KH_];
  #pragma unroll
  for (int k = 0; k < KH_; ++k) wt[k] = opaque(w1s[c1*KH_ + k]);
  float scale = bnp[c1], bias = bnp[40 + c1];
  if (!valid){ scale = __builtin_nanf(""); bias = scale; }  // NaN => both ballots false
  const float* xcol = &xs[w * XSTL];

  float xw[29];
  #pragma unroll
  for (int s = 0; s < 28; ++s) xw[s] = opaque(xcol[s]); // slots 0..27 = rows 0..27

  ulonglong2* obase = (ulonglong2*)s1bits + ((size_t)(b*12 + wd) * H_ + h0);

  #pragma unroll 1
  for (int c = 0; c < 5; ++c){                        // 5 chunks x 29 outputs = 145
    const float* xck = xcol + 29*c;
    ulonglong2* ob = obase + 29*c;
    S1(0)  S1(1)  S1(2)  S1(3)  S1(4)  S1(5)  S1(6)  S1(7)  S1(8)  S1(9)
    S1(10) S1(11) S1(12) S1(13) S1(14) S1(15) S1(16) S1(17) S1(18) S1(19)
    S1(20) S1(21) S1(22) S1(23) S1(24) S1(25) S1(26) S1(27) S1(28)
  }
  {                                                   // tail: outputs 145..149
    const float* xck = xcol + 145;
    ulonglong2* ob = obase + 145;
    S1(0) S1(1) S1(2) S1(3) S1(4)
  }
}

// ---- k2: conv2 + bn2 + prelu + pool + fc1 + bn3 + fc2, one block per batch ----
// Rows register-resident (lane=row); pooled signs ballot-packed in LDS; fc stages in-block.
__global__ __launch_bounds__(640) void k2_fused(const uint64_t* __restrict__ s1bits,
                                                const uint64_t* __restrict__ w2m_g,
                                                const uint64_t* __restrict__ fc1p,
                                                const int8_t* __restrict__ fc2s,
                                                const float* __restrict__ bnp,   // full table
                                                const float* __restrict__ a2p,
                                                const float* __restrict__ a3p,
                                                float* __restrict__ out)
{
  __shared__ float z[C2_][640];        // 102,400 B
  __shared__ uint64_t spP[FCW_], spN[FCW_];
  __shared__ int z3[FOUT_];
  int b = blockIdx.x;
  int tid = threadIdx.x;
  int lane = tid & 63;
  int rowc = (tid < H_) ? tid : (H_ - 1);

  uint64_t Pv[NWORDS_], Mv[NWORDS_];
  const ulonglong2* sb = (const ulonglong2*)s1bits + (size_t)b * NWORDS_ * H_;
  #pragma unroll
  for (int wd = 0; wd < NWORDS_; ++wd){
    ulonglong2 pm = sb[(size_t)wd * H_ + rowc];       // coalesced: lane=row
    Pv[wd] = pm.x; Mv[wd] = pm.y;
  }
  int nzv = 0;
  #pragma unroll
  for (int wd = 0; wd < NWORDS_; ++wd) nzv += __popcll(Mv[wd]);

  float alpha2 = a2p[0];
  #pragma unroll 2
  for (int c2 = 0; c2 < C2_; ++c2){
    int dsum = 0;
    #pragma unroll
    for (int wd = 0; wd < NWORDS_; ++wd)
      dsum += __popcll(Mv[wd] & (Pv[wd] ^ w2m_g[c2*NWORDS_ + wd]));  // WP uniform -> s_load
    int y = nzv - 2*dsum;
    float u = __fadd_rn(__fmul_rn((float)y, bnp[80 + c2]), bnp[120 + c2]);
    z[c2][tid] = (u >= 0.f) ? u : __fmul_rn(alpha2, u);
  }
  __syncthreads();

  // pool (sign(sum/30)==sign(sum), ascending r: bit-exact) + ballot-pack into spP/spN
  #pragma unroll 1
  for (int ch = 0; ch < 3; ++ch){
    int o = ch*640 + tid;
    bool act = (o < FIN_);
    int c2 = act ? (o / NJ_) : 0, j = act ? (o % NJ_) : 0;
    int base = 15*j;
    float s = 0.f;
    #pragma unroll
    for (int r = 0; r < 30; ++r) s = __fadd_rn(s, z[c2][base + r]);
    unsigned long long pp = __ballot(act && (s > 0.f));
    unsigned long long nn = __ballot(act && (s < 0.f));
    int word = ch*10 + (tid >> 6);
    if (lane == 0 && word < FCW_){ spP[word] = pp; spN[word] = nn; }
  }
  __syncthreads();

  // fc1 popcount (exact int) + bn3 + prelu + sign
  float alpha3 = a3p[0];
  if (tid < FOUT_){
    int o = tid;
    const uint64_t* wp = fc1p + o * (2*FCW_);
    int acc = 0;
    #pragma unroll
    for (int wd = 0; wd < FCW_; ++wd){
      uint64_t P = spP[wd], N = spN[wd];
      uint64_t WP = wp[wd], WN = wp[FCW_ + wd];
      acc += __popcll(P & WP) + __popcll(N & WN) - __popcll(P & WN) - __popcll(N & WP);
    }
    float u = __fadd_rn(__fmul_rn((float)acc, bnp[160 + o]), bnp[240 + o]);
    float zz = (u >= 0.f) ? u : __fmul_rn(alpha3, u);
    z3[o] = (zz > 0.f) - (zz < 0.f);
  }
  __syncthreads();
  if (tid < 2){
    int acc = 0;
    for (int o = 0; o < FOUT_; ++o) acc += z3[o] * (int)fc2s[tid * FOUT_ + o];
    out[b*2 + tid] = (float)acc;
  }
}

extern "C" void kernel_launch(void* const* d_in, const int* in_sizes, int n_in,
                              void* d_out, int out_size, void* d_ws, size_t ws_size,
                              hipStream_t stream)
{
  const float* x    = (const float*)d_in[0];
  const float* w1   = (const float*)d_in[1];
  const float* g1   = (const float*)d_in[2];
  const float* b1   = (const float*)d_in[3];
  const float* m1   = (const float*)d_in[4];
  const float* v1   = (const float*)d_in[5];
  const float* a1   = (const float*)d_in[6];   (void)a1;  // sign-invariant in k1
  const float* w2   = (const float*)d_in[7];
  const float* g2   = (const float*)d_in[8];
  const float* b2   = (const float*)d_in[9];
  const float* m2   = (const float*)d_in[10];
  const float* v2   = (const float*)d_in[11];
  const float* a2   = (const float*)d_in[12];
  const float* fc1w = (const float*)d_in[13];
  const float* g3   = (const float*)d_in[14];
  const float* b3   = (const float*)d_in[15];
  const float* m3   = (const float*)d_in[16];
  const float* v3   = (const float*)d_in[17];
  const float* a3   = (const float*)d_in[18];
  const float* fc2w = (const float*)d_in[19];

  char* ws = (char*)d_ws;
  uint64_t* s1bits = (uint64_t*)(ws);               // 256*12*600*16 = 29,491,200 B
  uint64_t* w2m    = (uint64_t*)(ws + 29491200);    // 3,840 B
  float*    w1s    = (float*)   (ws + 29495040);    // 4,640 B
  float*    bnp    = (float*)   (ws + 29499680);    // 1,280 B
  uint64_t* fc1p   = (uint64_t*)(ws + 29500960);    // 32,000 B
  int8_t*   fc2s   = (int8_t*)  (ws + 29532960);    // 160 B

  k0_setup<<<dim3(128), dim3(256), 0, stream>>>(w1, w2, fc1w, fc2w,
                                                g1, b1, m1, v1,
                                                g2, b2, m2, v2,
                                                g3, b3, m3, v3,
                                                w1s, w2m, fc1p, fc2s, bnp);
  k1_conv1<<<dim3(B_, 4, 3), dim3(256), 0, stream>>>(x, w1s, bnp, s1bits);
  k2_fused<<<dim3(B_), dim3(640), 0, stream>>>(s1bits, w2m, fc1p, fc2s, bnp,
                                               a2, a3, (float*)d_out);
}